// Round 17
// baseline (573.883 us; speedup 1.0000x reference)
//
#include <hip/hip_runtime.h>
#include <hip/hip_bf16.h>
#include <stdint.h>

#define NN 50000
#define EE 800000
#define HD 64
#define AGS 72   // aggf row stride: 64 feats + 3 trans + pad
#define SCL 1.4426950408889634f   // log2(e): folded into W1/b1/b2/cb1
#define LN2 0.6931471805599453f   // 1/SCL

typedef short short8 __attribute__((ext_vector_type(8)));
typedef float f32x4  __attribute__((ext_vector_type(4)));
typedef float f32x16 __attribute__((ext_vector_type(16)));
typedef uint  uint2v __attribute__((ext_vector_type(2)));

__device__ __forceinline__ float b2f(ushort u){ return __uint_as_float(((uint32_t)u)<<16); }
__device__ __forceinline__ ushort f2b(float f){
  uint32_t u = __float_as_uint(f);
  u += 0x7fffu + ((u>>16)&1u);
  return (ushort)(u>>16);
}
__device__ __forceinline__ uint pk2(float lo, float hi){
  union { __hip_bfloat162 b; uint u; } x;
  x.b = __float22bfloat162_rn(make_float2(lo, hi));
  return x.u;
}
__device__ __forceinline__ float silu_f(float x){
  return x * __builtin_amdgcn_rcpf(1.0f + __expf(-x));
}
__device__ __forceinline__ float exp2_fast(float x){
#if __has_builtin(__builtin_amdgcn_exp2f)
  return __builtin_amdgcn_exp2f(x);
#else
  float r; asm("v_exp_f32 %0, %1" : "=v"(r) : "v"(x)); return r;
#endif
}
// input xs = log2(e)*z ; returns log2(e)*silu(z). (e^-z == 2^-xs)
__device__ __forceinline__ float silu_s(float xs){
  return xs * __builtin_amdgcn_rcpf(1.0f + exp2_fast(-xs));
}

// ---------------- mega prep kernel: count+init+embed+packall ----------------
// weight packing layout (ushort elems in allp):
//   [0,9216)      eW1  32x32 frag, K=144 (9 kt): (k<131->eW1, k==131->eB1)*SCL, else 0 (identity k)
//   [9216,14336)  eW2  32x32 frag, K=80  (5 kt): kt<4 PI-PERMUTED k (matches uw register
//                 packing of GEMM1's D output); kt==4 identity bias row (eB2*SCL)
//   [14336,19456) cW1  32x32 frag, K=80  (5 kt): kt<4 PI-PERMUTED (matches uw2); kt==4 bias (cB1*SCL)
//   [19456,27648) nW1  16x16 frag, K=128 (4 kt): rows k>=64 (agg half) * (1/SCL)
//   [27648,31744) nW2  16x16 frag, K=64  (2 kt)
//   [31744,35840) vW1  16x16 frag, K=64  (2 kt)
__global__ __launch_bounds__(256) void k_prep(
    const int* __restrict__ erow, int* __restrict__ counts,
    const float* __restrict__ loc, const float* __restrict__ vel0,
    float4* __restrict__ coordw4, float4* __restrict__ velw4,
    const float* __restrict__ his, const float* __restrict__ embW,
    const float* __restrict__ embB, float* __restrict__ h, ushort* __restrict__ hb,
    const float* __restrict__ eW1, const float* __restrict__ eB1,
    const float* __restrict__ eW2, const float* __restrict__ eB2,
    const float* __restrict__ cW1, const float* __restrict__ cB1,
    const float* __restrict__ nW1, const float* __restrict__ nW2,
    const float* __restrict__ vW1, ushort* __restrict__ allp)
{
  int gid = blockIdx.x*256 + threadIdx.x;
  if (gid < NN*HD){
    int n = gid >> 6, j = gid & 63;
    float s = embB[j];
    #pragma unroll
    for (int k = 0; k < 8; ++k) s += his[n*8 + k] * embW[k*64 + j];
    h[gid] = s;
    hb[gid] = f2b(s);
  }
  if (gid < EE) atomicAdd(&counts[erow[gid]], 1);
  if (gid < NN){
    float vx = vel0[gid*3+0], vy = vel0[gid*3+1], vz = vel0[gid*3+2];
    float sp = sqrtf(vx*vx + vy*vy + vz*vz);
    velw4[gid] = make_float4(vx, vy, vz, sp);
    coordw4[gid] = make_float4(loc[gid*3+0], loc[gid*3+1], loc[gid*3+2], 0.0f);
  }
  if (gid < 35840){
    int idx = gid;
    float v;
    if (idx < 19456){
      int rel; const float* src; const float* bias; int mode; // 0=W1(K144,*SCL) identity, 2=pi+biasrow
      if (idx < 9216){ rel = idx; src = eW1; bias = eB1; mode = 0; }
      else if (idx < 14336){ rel = idx - 9216; src = eW2; bias = eB2; mode = 2; }
      else { rel = idx - 14336; src = cW1; bias = cB1; mode = 2; }
      int u = rel >> 9;           // (kt*2+mt)
      int kt = u >> 1, mt = u & 1;
      int within = rel & 511;
      int lane = within >> 3, i = within & 7;
      int col = mt*32 + (lane & 31);
      if (mode == 0){
        int k = kt*16 + (lane>>5)*8 + i;
        if (k < 131) v = src[k*64 + col] * SCL;
        else if (k == 131) v = bias[col] * SCL;
        else v = 0.0f;
      } else {
        if (kt < 4){
          // pi(k): matches uw/uw2 packing f = 32(kt>>1)+16(kt&1)+8(i>>2)+2((i>>1)&1)+(i&1)+4h
          int k = 32*(kt>>1) + 16*(kt&1) + 8*(i>>2) + 2*((i>>1)&1) + (i&1) + 4*(lane>>5);
          v = src[k*64 + col];
        } else {
          int k = 64 + (lane>>5)*8 + i;
          v = (k == 64) ? bias[col] * SCL : 0.0f;
        }
      }
    } else {
      int rel = idx - 19456;
      const float* src; int kt; int Ksrc; int isN1 = 0;
      if (rel < 8192){ src = nW1; kt = rel >> 11; Ksrc = 128; isN1 = 1; }
      else if (rel < 12288){ src = nW2; kt = (rel - 8192) >> 11; Ksrc = 64; }
      else { src = vW1; kt = (rel - 12288) >> 11; Ksrc = 64; }
      int within = rel & 2047;
      int i = within & 7;
      int lane = (within >> 3) & 63;
      int ct = (within >> 9) & 3;
      int k = kt*32 + (lane>>4)*8 + i;
      int col = ct*16 + (lane & 15);
      v = (k < Ksrc) ? src[k*64 + col] : 0.0f;
      if (isN1 && k >= 64) v *= LN2;   // undo SCL carried by aggregated m
    }
    allp[idx] = f2b(v);
  }
}

__global__ __launch_bounds__(256) void k_bsum(const int* __restrict__ counts, int* __restrict__ bsum){
  __shared__ int sm[4];
  int tid = threadIdx.x;
  int i = blockIdx.x*256 + tid;
  int v = (i < NN) ? counts[i] : 0;
  #pragma unroll
  for (int off = 1; off < 64; off <<= 1) v += __shfl_xor(v, off);
  if ((tid & 63) == 0) sm[tid >> 6] = v;
  __syncthreads();
  if (tid == 0) bsum[blockIdx.x] = sm[0] + sm[1] + sm[2] + sm[3];
}

__global__ __launch_bounds__(256) void k_bscan(const int* __restrict__ bsum, int* __restrict__ bbase){
  __shared__ int sm[256];
  int tid = threadIdx.x;
  int v = (tid < 196) ? bsum[tid] : 0;
  sm[tid] = v;
  __syncthreads();
  #pragma unroll
  for (int off = 1; off < 256; off <<= 1){
    int t = (tid >= off) ? sm[tid - off] : 0;
    __syncthreads();
    sm[tid] += t;
    __syncthreads();
  }
  if (tid < 196) bbase[tid] = sm[tid] - v;   // exclusive
}

__global__ __launch_bounds__(256) void k_scatter(const int* __restrict__ counts,
    const int* __restrict__ bbase, int* __restrict__ cursor){
  __shared__ int sm[256];
  int tid = threadIdx.x;
  int i = blockIdx.x*256 + tid;
  int v = (i < NN) ? counts[i] : 0;
  sm[tid] = v;
  __syncthreads();
  #pragma unroll
  for (int off = 1; off < 256; off <<= 1){
    int t = (tid >= off) ? sm[tid - off] : 0;
    __syncthreads();
    sm[tid] += t;
    __syncthreads();
  }
  if (i < NN) cursor[i] = bbase[blockIdx.x] + sm[tid] - v;
}

__global__ __launch_bounds__(256) void k_fill(const int* __restrict__ erow,
    const int* __restrict__ ecol, const float* __restrict__ eattr,
    int* __restrict__ cursor, int4* __restrict__ erec){
  int e = blockIdx.x*256 + threadIdx.x;
  if (e < EE){
    int r = erow[e];
    int pos = atomicAdd(&cursor[r], 1);
    int4 rec;
    rec.x = r;
    rec.y = ecol[e];
    rec.z = __float_as_int(eattr[(size_t)e*2 + 0]);
    rec.w = __float_as_int(eattr[(size_t)e*2 + 1]);
    erec[pos] = rec;
  }
}

// ---------------- edge MFMA kernel: 32x32x16, all-swapped, FULL REGISTER CHAIN ----------------
// GEMM1 -> uw (pi-order regs) -> GEMM2 (pi-packed W2) -> uw2 -> GEMM3 (pi-packed cW1).
// X1 never touches LDS; LDS holds only m (for seg-sum) + trans. Both-mt ILP everywhere.
// 128-thr blocks + launch_bounds(128,5): 102-reg budget, 5 waves/SIMD (r15 proved the
// occupancy; r8 proved the pi algebra; r14/r16 proved both-mt bodies).
__global__ __launch_bounds__(128, 5) void k_edge(
    const ushort* __restrict__ hb, const float4* __restrict__ coord4,
    const int4* __restrict__ erec,
    const ushort* __restrict__ W1p, const ushort* __restrict__ W2p, const ushort* __restrict__ C1p,
    const float* __restrict__ cw2,
    float* __restrict__ aggf)
{
  __shared__ __align__(16) uint XMT[64*38];
  const int tid = threadIdx.x;
  const int wave = tid >> 6, lane = tid & 63;
  const int e = lane & 31, h = lane >> 5;
  const int wt = wave * 32;

  // bijective XCD swizzle: nwg=12500, q=1562, r=4
  const int bid = blockIdx.x;
  const int xcd = bid & 7, bx = bid >> 3;
  const int swz = (xcd < 4) ? (xcd*1563 + bx) : (4*1563 + (xcd-4)*1562 + bx);
  const int slot = swz*64 + wt + e;

  int4 er = erec[slot];
  const int rA = er.x, cA = er.y;

  float4 crd = coord4[rA], ccd = coord4[cA];
  float dx = crd.x-ccd.x, dy = crd.y-ccd.y, dz = crd.z-ccd.z;
  float radial = dx*dx + dy*dy + dz*dz;

  const short8* W1f = reinterpret_cast<const short8*>(W1p);
  const short8* W2f = reinterpret_cast<const short8*>(W2p);
  const short8* C1f = reinterpret_cast<const short8*>(C1p);
  const int wrow = (wt + e)*38;

  // constant-1 B-frag (k==64 slot) for bias rows of GEMM2/3
  short8 ones8 = {0,0,0,0,0,0,0,0};
  if (h == 0) ones8[0] = (short)0x3F80;

  union U4 { uint u[4]; short8 s; };

  // GEMM1: bias folded at k=131 (weights pre-scaled by SCL); both-mt ILP -> uw regs
  uint uw[16];
  {
    short8 bf[9];
    #pragma unroll
    for (int kt = 0; kt < 4; ++kt)
      bf[kt] = *reinterpret_cast<const short8*>(hb + (size_t)rA*HD + kt*16 + h*8);
    #pragma unroll
    for (int kt = 0; kt < 4; ++kt)
      bf[4+kt] = *reinterpret_cast<const short8*>(hb + (size_t)cA*HD + kt*16 + h*8);
    short8 t8 = {0,0,0,0,0,0,0,0};
    if (h == 0){
      t8[0] = (short)f2b(radial);
      t8[1] = (short)f2b(__int_as_float(er.z));
      t8[2] = (short)f2b(__int_as_float(er.w));
      t8[3] = (short)0x3F80;   // 1.0 -> pairs with b1*SCL packed at k=131
    }
    bf[8] = t8;

    f32x16 a0, a1;
    #pragma unroll
    for (int r = 0; r < 16; ++r){ a0[r] = 0.0f; a1[r] = 0.0f; }
    __builtin_amdgcn_s_setprio(1);
    #pragma unroll
    for (int kt = 0; kt < 9; ++kt)
      a0 = __builtin_amdgcn_mfma_f32_32x32x16_bf16(W1f[(kt*2+0)*64 + lane], bf[kt], a0, 0,0,0);
    #pragma unroll
    for (int kt = 0; kt < 9; ++kt)
      a1 = __builtin_amdgcn_mfma_f32_32x32x16_bf16(W1f[(kt*2+1)*64 + lane], bf[kt], a1, 0,0,0);
    __builtin_amdgcn_s_setprio(0);
    #pragma unroll
    for (int s = 0; s < 8; ++s) uw[s]   = pk2(silu_s(a0[2*s]), silu_s(a0[2*s+1]));
    #pragma unroll
    for (int s = 0; s < 8; ++s) uw[8+s] = pk2(silu_s(a1[2*s]), silu_s(a1[2*s+1]));
  }

  // GEMM2: m = silu(X1 @ W2 + b2), K=80; B-frags = uw words directly (pi-packed W2)
  uint uw2[16];
  {
    f32x16 a0, a1;
    #pragma unroll
    for (int r = 0; r < 16; ++r){ a0[r] = 0.0f; a1[r] = 0.0f; }
    __builtin_amdgcn_s_setprio(1);
    #pragma unroll
    for (int kt = 0; kt < 4; ++kt){
      U4 t; t.u[0]=uw[4*kt+0]; t.u[1]=uw[4*kt+1]; t.u[2]=uw[4*kt+2]; t.u[3]=uw[4*kt+3];
      a0 = __builtin_amdgcn_mfma_f32_32x32x16_bf16(W2f[(kt*2+0)*64 + lane], t.s, a0, 0,0,0);
    }
    a0 = __builtin_amdgcn_mfma_f32_32x32x16_bf16(W2f[(4*2+0)*64 + lane], ones8, a0, 0,0,0);
    #pragma unroll
    for (int kt = 0; kt < 4; ++kt){
      U4 t; t.u[0]=uw[4*kt+0]; t.u[1]=uw[4*kt+1]; t.u[2]=uw[4*kt+2]; t.u[3]=uw[4*kt+3];
      a1 = __builtin_amdgcn_mfma_f32_32x32x16_bf16(W2f[(kt*2+1)*64 + lane], t.s, a1, 0,0,0);
    }
    a1 = __builtin_amdgcn_mfma_f32_32x32x16_bf16(W2f[(4*2+1)*64 + lane], ones8, a1, 0,0,0);
    __builtin_amdgcn_s_setprio(0);
    #pragma unroll
    for (int s = 0; s < 8; ++s) uw2[s]   = pk2(silu_s(a0[2*s]), silu_s(a0[2*s+1]));
    #pragma unroll
    for (int s = 0; s < 8; ++s) uw2[8+s] = pk2(silu_s(a1[2*s]), silu_s(a1[2*s+1]));
    // m -> LDS (uw2-order: lane h writes uints h*16..h*16+15); store latency
    // hides under GEMM3 (no read-back before seg-sum).
    #pragma unroll
    for (int t = 0; t < 8; ++t)
      *reinterpret_cast<uint2v*>(&XMT[wrow + h*16 + 2*t]) = (uint2v){uw2[2*t], uw2[2*t+1]};
  }

  // GEMM3: X3 = silu(m @ cW1 + cb1), K=80 ; w = (X3s @ cw2) * LN2.
  // B-frags = uw2 words directly (pi-packed cW1).
  float pw = 0.0f;
  {
    f32x16 a0, a1;
    #pragma unroll
    for (int r = 0; r < 16; ++r){ a0[r] = 0.0f; a1[r] = 0.0f; }
    __builtin_amdgcn_s_setprio(1);
    #pragma unroll
    for (int kt = 0; kt < 4; ++kt){
      U4 t; t.u[0]=uw2[4*kt+0]; t.u[1]=uw2[4*kt+1]; t.u[2]=uw2[4*kt+2]; t.u[3]=uw2[4*kt+3];
      a0 = __builtin_amdgcn_mfma_f32_32x32x16_bf16(C1f[(kt*2+0)*64 + lane], t.s, a0, 0,0,0);
    }
    a0 = __builtin_amdgcn_mfma_f32_32x32x16_bf16(C1f[(4*2+0)*64 + lane], ones8, a0, 0,0,0);
    #pragma unroll
    for (int kt = 0; kt < 4; ++kt){
      U4 t; t.u[0]=uw2[4*kt+0]; t.u[1]=uw2[4*kt+1]; t.u[2]=uw2[4*kt+2]; t.u[3]=uw2[4*kt+3];
      a1 = __builtin_amdgcn_mfma_f32_32x32x16_bf16(C1f[(kt*2+1)*64 + lane], t.s, a1, 0,0,0);
    }
    a1 = __builtin_amdgcn_mfma_f32_32x32x16_bf16(C1f[(4*2+1)*64 + lane], ones8, a1, 0,0,0);
    __builtin_amdgcn_s_setprio(0);
    #pragma unroll
    for (int q = 0; q < 4; ++q){
      f32x4 cwq = *reinterpret_cast<const f32x4*>(cw2 + q*8 + h*4);
      #pragma unroll
      for (int r = 0; r < 4; ++r) pw += silu_s(a0[4*q+r]) * cwq[r];
    }
    #pragma unroll
    for (int q = 0; q < 4; ++q){
      f32x4 cwq = *reinterpret_cast<const f32x4*>(cw2 + 32 + q*8 + h*4);
      #pragma unroll
      for (int r = 0; r < 4; ++r) pw += silu_s(a1[4*q+r]) * cwq[r];
    }
  }
  pw += __shfl_xor(pw, 32);
  pw *= LN2;   // undo SCL carried by X3
  if (h == 0){
    // trans -> XMT spare columns (uints 32..34 of this edge's row)
    *reinterpret_cast<uint2v*>(&XMT[wrow + 32]) =
        (uint2v){__float_as_uint(dx*pw), __float_as_uint(dy*pw)};
    XMT[wrow + 34] = __float_as_uint(dz*pw);
  }
  __builtin_amdgcn_sched_barrier(0);

  // per-wave segmented sum over 32 CSR-sorted edges.
  // m is in uw2-order: feature j at ushort offset soff(j) within the row.
  // m values carry SCL; k_node's nW1 agg rows are pre-divided by SCL.
  // Interior segments are wave-exclusive (CSR) -> plain store.
  const int j = lane;
  const int soff = (((j>>5)*8 + ((j>>3)&3)*2 + ((j>>1)&1)) + ((j>>2)&1)*16)*2 + (j&1);
  const ushort* mvals = reinterpret_cast<const ushort*>(XMT);
  const float*  tvals = reinterpret_cast<const float*>(XMT);
  float sum = 0.f, ts = 0.f;
  int rcur = __builtin_amdgcn_readlane(rA, 0);
  int segstart = 0;
  #pragma unroll
  for (int i = 0; i < 32; ++i){
    sum += b2f(mvals[(wt + i)*76 + soff]);
    if (lane < 3) ts += tvals[(wt + i)*38 + 32 + lane];
    int rnext = (i < 31) ? __builtin_amdgcn_readlane(rA, i+1) : -1;
    if (rnext != rcur){
      if (segstart == 0 || i == 31){
        atomicAdd(&aggf[(size_t)rcur*AGS + lane], sum);
        if (lane < 3) atomicAdd(&aggf[(size_t)rcur*AGS + 64 + lane], ts);
      } else {
        aggf[(size_t)rcur*AGS + lane] = sum;
        if (lane < 3) aggf[(size_t)rcur*AGS + 64 + lane] = ts;
      }
      sum = 0.f; ts = 0.f; rcur = rnext; segstart = i + 1;
    }
  }
}

// ---------------- node MFMA kernel (+fused vel/coord update, +aggf re-zero) ----------------
__global__ __launch_bounds__(256) void k_node(
    const ushort* __restrict__ hb, float* __restrict__ aggf, const float* __restrict__ h_in,
    const ushort* __restrict__ nW1p, const ushort* __restrict__ nW2p, const ushort* __restrict__ vW1p,
    const float* __restrict__ nb1, const float* __restrict__ nb2,
    const float* __restrict__ vb1, const float* __restrict__ vW2, const float* __restrict__ vb2,
    const int* __restrict__ counts, float4* __restrict__ velw4, float4* __restrict__ coordw4,
    float* __restrict__ h_out, ushort* __restrict__ hb_out,
    float* __restrict__ xout, float* __restrict__ vout, int last)
{
  __shared__ __align__(16) ushort HID[64*88];
  __shared__ float VS[64];
  const int tid = threadIdx.x;
  const int wave = tid >> 6, lane = tid & 63;
  const int c = lane & 15, g = lane >> 4;
  const int wt = wave * 16;
  const int nbase = blockIdx.x * 64;
  int nA = nbase + wt + c;
  int nAc = (nA < NN) ? nA : (NN-1);

  short8 af[4];
  af[0] = *reinterpret_cast<const short8*>(hb + (size_t)nAc*HD + g*8);
  af[1] = *reinterpret_cast<const short8*>(hb + (size_t)nAc*HD + 32 + g*8);
  {
    const float* ag = aggf + (size_t)nAc*AGS;
    f32x4 q0 = *reinterpret_cast<const f32x4*>(ag + g*8);
    f32x4 q1 = *reinterpret_cast<const f32x4*>(ag + g*8 + 4);
    f32x4 q2 = *reinterpret_cast<const f32x4*>(ag + 32 + g*8);
    f32x4 q3 = *reinterpret_cast<const f32x4*>(ag + 32 + g*8 + 4);
    union FB { ushort u[8]; short8 s; };
    FB f2_, f3_;
    #pragma unroll
    for (int i = 0; i < 4; ++i){ f2_.u[i] = f2b(q0[i]); f2_.u[4+i] = f2b(q1[i]); }
    #pragma unroll
    for (int i = 0; i < 4; ++i){ f3_.u[i] = f2b(q2[i]); f3_.u[4+i] = f2b(q3[i]); }
    af[2] = f2_.s;
    af[3] = f3_.s;
  }
  const short8* N1f = reinterpret_cast<const short8*>(nW1p);
  const short8* N2f = reinterpret_cast<const short8*>(nW2p);
  const short8* V1f = reinterpret_cast<const short8*>(vW1p);

  f32x4 acc[4];
  #pragma unroll
  for (int ct = 0; ct < 4; ++ct){
    float bb = nb1[ct*16 + c];
    acc[ct] = (f32x4){bb,bb,bb,bb};
  }
  #pragma unroll
  for (int kt = 0; kt < 4; ++kt){
    #pragma unroll
    for (int ct = 0; ct < 4; ++ct){
      acc[ct] = __builtin_amdgcn_mfma_f32_16x16x32_bf16(af[kt], N1f[(kt*4+ct)*64 + lane], acc[ct], 0,0,0);
    }
  }
  #pragma unroll
  for (int ct = 0; ct < 4; ++ct){
    int col = ct*16 + c;
    #pragma unroll
    for (int r = 0; r < 4; ++r){
      HID[(wt + g*4 + r)*88 + col] = f2b(silu_f(acc[ct][r]));
    }
  }

  // v MLP (uses h only)
  f32x4 av[4];
  #pragma unroll
  for (int ct = 0; ct < 4; ++ct){
    float bb = vb1[ct*16 + c];
    av[ct] = (f32x4){bb,bb,bb,bb};
  }
  #pragma unroll
  for (int kt = 0; kt < 2; ++kt){
    #pragma unroll
    for (int ct = 0; ct < 4; ++ct){
      av[ct] = __builtin_amdgcn_mfma_f32_16x16x32_bf16(af[kt], V1f[(kt*4+ct)*64 + lane], av[ct], 0,0,0);
    }
  }
  float pw[4] = {0.f,0.f,0.f,0.f};
  #pragma unroll
  for (int ct = 0; ct < 4; ++ct){
    float vw = vW2[ct*16 + c];
    #pragma unroll
    for (int r = 0; r < 4; ++r) pw[r] += silu_f(av[ct][r]) * vw;
  }
  #pragma unroll
  for (int off = 1; off < 16; off <<= 1){
    #pragma unroll
    for (int r = 0; r < 4; ++r) pw[r] += __shfl_xor(pw[r], off, 16);
  }
  if (c == 0){
    float vbias = vb2[0];
    #pragma unroll
    for (int r = 0; r < 4; ++r) VS[wt + g*4 + r] = pw[r] + vbias;
  }

  // node MLP second layer (reads HID written by this wave only)
  short8 h0 = *reinterpret_cast<const short8*>(&HID[(wt + c)*88 + g*8]);
  short8 h1 = *reinterpret_cast<const short8*>(&HID[(wt + c)*88 + 32 + g*8]);
  f32x4 a2[4];
  #pragma unroll
  for (int ct = 0; ct < 4; ++ct){
    float bb = nb2[ct*16 + c];
    a2[ct] = (f32x4){bb,bb,bb,bb};
  }
  #pragma unroll
  for (int ct = 0; ct < 4; ++ct)
    a2[ct] = __builtin_amdgcn_mfma_f32_16x16x32_bf16(h0, N2f[(0*4+ct)*64 + lane], a2[ct], 0,0,0);
  #pragma unroll
  for (int ct = 0; ct < 4; ++ct)
    a2[ct] = __builtin_amdgcn_mfma_f32_16x16x32_bf16(h1, N2f[(1*4+ct)*64 + lane], a2[ct], 0,0,0);
  #pragma unroll
  for (int ct = 0; ct < 4; ++ct){
    int col = ct*16 + c;
    #pragma unroll
    for (int r = 0; r < 4; ++r){
      int n = nbase + wt + g*4 + r;
      if (n < NN){
        size_t off = (size_t)n*HD + col;
        float v = 2.0f*h_in[off] + a2[ct][r];
        h_out[off] = v;
        hb_out[off] = f2b(v);
      }
    }
  }

  // fused vel/coord update
  __syncthreads();
  if (tid < 64){
    int n = nbase + tid;
    if (n < NN){
      float vsn = VS[tid];
      float inv = 1.0f / fmaxf((float)counts[n], 1.0f);
      const float* ag = aggf + (size_t)n*AGS + 64;
      float ax = ag[0]*inv, ay = ag[1]*inv, az = ag[2]*inv;
      float4 vv = velw4[n];
      float4 cc = coordw4[n];
      float v0 = vsn*vv.x + ax*(1.0f/7.0f);
      float v1 = vsn*vv.y + ay*(1.0f/7.0f);
      float v2 = vsn*vv.z + az*(1.0f/7.0f);
      float s = vv.w / (sqrtf(v0*v0 + v1*v1 + v2*v2) + 1e-8f);
      v0 *= s; v1 *= s; v2 *= s;
      float c0 = cc.x + v0*(1.0f/7.0f);
      float c1 = cc.y + v1*(1.0f/7.0f);
      float c2 = cc.z + v2*(1.0f/7.0f);
      if (last){
        vout[n*3+0] = v0; vout[n*3+1] = v1; vout[n*3+2] = v2;
        xout[n*3+0] = c0; xout[n*3+1] = c1; xout[n*3+2] = c2;
      } else {
        velw4[n] = make_float4(v0, v1, v2, vv.w);
        coordw4[n] = make_float4(c0, c1, c2, 0.0f);
      }
    }
  }

  // re-zero this block's aggf rows for the next layer (vectorized)
  __syncthreads();
  int nvalid = NN - nbase; if (nvalid > 64) nvalid = 64;
  f32x4* zb4 = reinterpret_cast<f32x4*>(aggf + (size_t)nbase*AGS);
  f32x4 z4 = {0.f,0.f,0.f,0.f};
  for (int idx2 = tid; idx2 < nvalid*(AGS/4); idx2 += 256) zb4[idx2] = z4;
}

// ---------------- launcher ----------------
extern "C" void kernel_launch(void* const* d_in, const int* in_sizes, int n_in,
                              void* d_out, int out_size, void* d_ws, size_t ws_size,
                              hipStream_t stream)
{
  const float* his  = (const float*)d_in[0];
  const float* loc  = (const float*)d_in[1];
  const int*   edges= (const int*)d_in[2];
  const float* vel0 = (const float*)d_in[3];
  const float* eatt = (const float*)d_in[4];
  const float* embW = (const float*)d_in[5];
  const float* embB = (const float*)d_in[6];
  const float* eW1  = (const float*)d_in[7];
  const float* eB1  = (const float*)d_in[8];
  const float* eW2  = (const float*)d_in[9];
  const float* eB2  = (const float*)d_in[10];
  const float* cW1  = (const float*)d_in[11];
  const float* cB1  = (const float*)d_in[12];
  const float* cW2  = (const float*)d_in[13];
  const float* vW1  = (const float*)d_in[14];
  const float* vB1  = (const float*)d_in[15];
  const float* vW2  = (const float*)d_in[16];
  const float* vB2  = (const float*)d_in[17];
  const float* nW1  = (const float*)d_in[18];
  const float* nB1  = (const float*)d_in[19];
  const float* nW2  = (const float*)d_in[20];
  const float* nB2  = (const float*)d_in[21];
  const int* erow = edges;
  const int* ecol = edges + EE;

  char* ws = (char*)d_ws;
  size_t off = 0;
  auto alloc = [&](size_t bytes)->char*{
    char* p = ws + off;
    off = (off + bytes + 255) & ~(size_t)255;
    return p;
  };
  ushort* hb     = (ushort*)alloc((size_t)NN*HD*2);
  int*    counts = (int*)   alloc((size_t)NN*4);       // counts..aggf contiguous: one memset
  float*  aggf   = (float*) alloc((size_t)NN*AGS*4);
  int*    cursor = (int*)   alloc((size_t)NN*4);
  int*    bsum   = (int*)   alloc(256*4);
  int*    bbase  = (int*)   alloc(256*4);
  float4* coordw4= (float4*)alloc((size_t)NN*16);
  float4* velw4  = (float4*)alloc((size_t)NN*16);
  ushort* allp   = (ushort*)alloc(35840*2);
  int4*   erec   = (int4*)  alloc((size_t)EE*16);

  ushort* eW1p32 = allp;            // 9216
  ushort* eW2p32 = allp + 9216;     // 5120 (pi-packed, K=80 bias row)
  ushort* cW1p32 = allp + 14336;    // 5120 (pi-packed, K=80 bias row)
  ushort* nW1p   = allp + 19456;    // 8192
  ushort* nW2p   = allp + 27648;    // 4096
  ushort* vW1p   = allp + 31744;    // 4096

  float* xout = (float*)d_out;                    // [N,3]
  float* hout = (float*)d_out + (size_t)NN*3;     // [N,64] — doubles as fp32 h buffer
  float* vout = (float*)d_out + (size_t)NN*3 + (size_t)NN*HD; // [N,3]

  // single memset spanning counts (incl. 256B pad) + aggf
  size_t counts_pad = ((size_t)NN*4 + 255) & ~(size_t)255;
  hipMemsetAsync(counts, 0, counts_pad + (size_t)NN*AGS*4, stream);
  k_prep<<<12500,256,0,stream>>>(erow, counts, loc, vel0, coordw4, velw4,
      his, embW, embB, hout, hb,
      eW1, eB1, eW2, eB2, cW1, cB1, nW1, nW2, vW1, allp);
  k_bsum<<<196,256,0,stream>>>(counts, bsum);
  k_bscan<<<1,256,0,stream>>>(bsum, bbase);
  k_scatter<<<196,256,0,stream>>>(counts, bbase, cursor);
  k_fill<<<3125,256,0,stream>>>(erow, ecol, eatt, cursor, erec);

  for (int L = 0; L < 4; ++L){
    k_edge<<<12500,128,0,stream>>>(hb, coordw4, erec,
        eW1p32, eW2p32, cW1p32, cW2, aggf);
    k_node<<<782,256,0,stream>>>(hb, aggf, hout, nW1p, nW2p, vW1p,
        nB1, nB2, vB1, vW2, vB2, counts, velw4, coordw4,
        hout, hb, xout, vout, (L==3) ? 1 : 0);
  }
}

// Round 18
// 451.001 us; speedup vs baseline: 1.2725x; 1.2725x over previous
//
#include <hip/hip_runtime.h>
#include <hip/hip_bf16.h>
#include <stdint.h>

#define NN 50000
#define EE 800000
#define HD 64
#define AGS 72   // aggf row stride: 64 feats + 3 trans + pad
#define SCL 1.4426950408889634f   // log2(e): folded into W1/b1/b2/cb1
#define LN2 0.6931471805599453f   // 1/SCL

typedef short short8 __attribute__((ext_vector_type(8)));
typedef float f32x4  __attribute__((ext_vector_type(4)));
typedef float f32x16 __attribute__((ext_vector_type(16)));
typedef uint  uint2v __attribute__((ext_vector_type(2)));

__device__ __forceinline__ float b2f(ushort u){ return __uint_as_float(((uint32_t)u)<<16); }
__device__ __forceinline__ ushort f2b(float f){
  uint32_t u = __float_as_uint(f);
  u += 0x7fffu + ((u>>16)&1u);
  return (ushort)(u>>16);
}
__device__ __forceinline__ uint pk2(float lo, float hi){
  union { __hip_bfloat162 b; uint u; } x;
  x.b = __float22bfloat162_rn(make_float2(lo, hi));
  return x.u;
}
__device__ __forceinline__ float silu_f(float x){
  return x * __builtin_amdgcn_rcpf(1.0f + __expf(-x));
}
__device__ __forceinline__ float exp2_fast(float x){
#if __has_builtin(__builtin_amdgcn_exp2f)
  return __builtin_amdgcn_exp2f(x);
#else
  float r; asm("v_exp_f32 %0, %1" : "=v"(r) : "v"(x)); return r;
#endif
}
// input xs = log2(e)*z ; returns log2(e)*silu(z). (e^-z == 2^-xs)
__device__ __forceinline__ float silu_s(float xs){
  return xs * __builtin_amdgcn_rcpf(1.0f + exp2_fast(-xs));
}

// ---------------- mega prep kernel: count+init+embed+packall ----------------
// weight packing layout (ushort elems in allp):
//   [0,9216)      eW1  32x32 frag, K=144 (9 kt): (k<131->eW1, k==131->eB1)*SCL, else 0
//   [9216,14336)  eW2  32x32 frag, K=80  (5 kt): k<64->eW2, k==64->eB2*SCL, else 0
//   [14336,19456) cW1  32x32 frag, K=80  (5 kt): k<64->cW1, k==64->cB1*SCL, else 0
//   [19456,27648) nW1  16x16 frag, K=128 (4 kt): rows k>=64 (agg half) * (1/SCL)
//   [27648,31744) nW2  16x16 frag, K=64  (2 kt)
//   [31744,35840) vW1  16x16 frag, K=64  (2 kt)
__global__ __launch_bounds__(256) void k_prep(
    const int* __restrict__ erow, int* __restrict__ counts,
    const float* __restrict__ loc, const float* __restrict__ vel0,
    float4* __restrict__ coordw4, float4* __restrict__ velw4,
    const float* __restrict__ his, const float* __restrict__ embW,
    const float* __restrict__ embB, float* __restrict__ h, ushort* __restrict__ hb,
    const float* __restrict__ eW1, const float* __restrict__ eB1,
    const float* __restrict__ eW2, const float* __restrict__ eB2,
    const float* __restrict__ cW1, const float* __restrict__ cB1,
    const float* __restrict__ nW1, const float* __restrict__ nW2,
    const float* __restrict__ vW1, ushort* __restrict__ allp)
{
  int gid = blockIdx.x*256 + threadIdx.x;
  if (gid < NN*HD){
    int n = gid >> 6, j = gid & 63;
    float s = embB[j];
    #pragma unroll
    for (int k = 0; k < 8; ++k) s += his[n*8 + k] * embW[k*64 + j];
    h[gid] = s;
    hb[gid] = f2b(s);
  }
  if (gid < EE) atomicAdd(&counts[erow[gid]], 1);
  if (gid < NN){
    float vx = vel0[gid*3+0], vy = vel0[gid*3+1], vz = vel0[gid*3+2];
    float sp = sqrtf(vx*vx + vy*vy + vz*vz);
    velw4[gid] = make_float4(vx, vy, vz, sp);
    coordw4[gid] = make_float4(loc[gid*3+0], loc[gid*3+1], loc[gid*3+2], 0.0f);
  }
  if (gid < 35840){
    int idx = gid;
    float v;
    if (idx < 19456){
      int rel; const float* src; const float* bias; int mode; // 0=W1(K144,*SCL), 1=ext80
      if (idx < 9216){ rel = idx; src = eW1; bias = eB1; mode = 0; }
      else if (idx < 14336){ rel = idx - 9216; src = eW2; bias = eB2; mode = 1; }
      else { rel = idx - 14336; src = cW1; bias = cB1; mode = 1; }
      int u = rel >> 9;           // (kt*2+mt)
      int kt = u >> 1, mt = u & 1;
      int within = rel & 511;
      int lane = within >> 3, i = within & 7;
      int k = kt*16 + (lane>>5)*8 + i;
      int col = mt*32 + (lane & 31);
      if (mode == 0){
        if (k < 131) v = src[k*64 + col] * SCL;
        else if (k == 131) v = bias[col] * SCL;
        else v = 0.0f;
      } else {
        if (k < 64) v = src[k*64 + col];
        else if (k == 64) v = bias[col] * SCL;
        else v = 0.0f;
      }
    } else {
      int rel = idx - 19456;
      const float* src; int kt; int Ksrc; int isN1 = 0;
      if (rel < 8192){ src = nW1; kt = rel >> 11; Ksrc = 128; isN1 = 1; }
      else if (rel < 12288){ src = nW2; kt = (rel - 8192) >> 11; Ksrc = 64; }
      else { src = vW1; kt = (rel - 12288) >> 11; Ksrc = 64; }
      int within = rel & 2047;
      int i = within & 7;
      int lane = (within >> 3) & 63;
      int ct = (within >> 9) & 3;
      int k = kt*32 + (lane>>4)*8 + i;
      int col = ct*16 + (lane & 15);
      v = (k < Ksrc) ? src[k*64 + col] : 0.0f;
      if (isN1 && k >= 64) v *= LN2;   // undo SCL carried by aggregated m
    }
    allp[idx] = f2b(v);
  }
}

__global__ __launch_bounds__(256) void k_bsum(const int* __restrict__ counts, int* __restrict__ bsum){
  __shared__ int sm[4];
  int tid = threadIdx.x;
  int i = blockIdx.x*256 + tid;
  int v = (i < NN) ? counts[i] : 0;
  #pragma unroll
  for (int off = 1; off < 64; off <<= 1) v += __shfl_xor(v, off);
  if ((tid & 63) == 0) sm[tid >> 6] = v;
  __syncthreads();
  if (tid == 0) bsum[blockIdx.x] = sm[0] + sm[1] + sm[2] + sm[3];
}

__global__ __launch_bounds__(256) void k_bscan(const int* __restrict__ bsum, int* __restrict__ bbase){
  __shared__ int sm[256];
  int tid = threadIdx.x;
  int v = (tid < 196) ? bsum[tid] : 0;
  sm[tid] = v;
  __syncthreads();
  #pragma unroll
  for (int off = 1; off < 256; off <<= 1){
    int t = (tid >= off) ? sm[tid - off] : 0;
    __syncthreads();
    sm[tid] += t;
    __syncthreads();
  }
  if (tid < 196) bbase[tid] = sm[tid] - v;   // exclusive
}

__global__ __launch_bounds__(256) void k_scatter(const int* __restrict__ counts,
    const int* __restrict__ bbase, int* __restrict__ cursor){
  __shared__ int sm[256];
  int tid = threadIdx.x;
  int i = blockIdx.x*256 + tid;
  int v = (i < NN) ? counts[i] : 0;
  sm[tid] = v;
  __syncthreads();
  #pragma unroll
  for (int off = 1; off < 256; off <<= 1){
    int t = (tid >= off) ? sm[tid - off] : 0;
    __syncthreads();
    sm[tid] += t;
    __syncthreads();
  }
  if (i < NN) cursor[i] = bbase[blockIdx.x] + sm[tid] - v;
}

__global__ __launch_bounds__(256) void k_fill(const int* __restrict__ erow,
    const int* __restrict__ ecol, const float* __restrict__ eattr,
    int* __restrict__ cursor, int4* __restrict__ erec){
  int e = blockIdx.x*256 + threadIdx.x;
  if (e < EE){
    int r = erow[e];
    int pos = atomicAdd(&cursor[r], 1);
    int4 rec;
    rec.x = r;
    rec.y = ecol[e];
    rec.z = __float_as_int(eattr[(size_t)e*2 + 0]);
    rec.w = __float_as_int(eattr[(size_t)e*2 + 1]);
    erec[pos] = rec;
  }
}

// ---------------- edge MFMA kernel: 32x32x16, all-swapped, 1-WAVE BLOCKS ----------------
// r11 bodies (both-mt ILP everywhere, exp2-prescaled weights, K=80 bias rows,
// setprio, trans in XMT spare cols, interior plain-store seg-sum).
// Block = 64 threads = 1 wave; k_edge has NO __syncthreads (wave-private LDS),
// so 1-wave blocks release regs/LDS on retire immediately (no block-tail).
// SESSION BEST CONFIG (r14: 453.7 us). All alternative quadrants measured worse:
// seq-mt (r13/r15), (256,6)/(128,5) reg caps (r12/r17 spills), 2-tile prefetch (r9),
// full register chain (r8/r17).
__global__ __launch_bounds__(64, 4) void k_edge(
    const ushort* __restrict__ hb, const float4* __restrict__ coord4,
    const int4* __restrict__ erec,
    const ushort* __restrict__ W1p, const ushort* __restrict__ W2p, const ushort* __restrict__ C1p,
    const float* __restrict__ cw2,
    float* __restrict__ aggf)
{
  __shared__ __align__(16) uint XMT[32*38];
  const int lane = threadIdx.x & 63;
  const int e = lane & 31, h = lane >> 5;

  // bijective XCD swizzle: nwg=25000 (divisible by 8)
  const int bid = blockIdx.x;
  const int swz = (bid & 7)*3125 + (bid >> 3);
  const int slot = swz*32 + e;

  int4 er = erec[slot];
  const int rA = er.x, cA = er.y;

  float4 crd = coord4[rA], ccd = coord4[cA];
  float dx = crd.x-ccd.x, dy = crd.y-ccd.y, dz = crd.z-ccd.z;
  float radial = dx*dx + dy*dy + dz*dz;

  const short8* W1f = reinterpret_cast<const short8*>(W1p);
  const short8* W2f = reinterpret_cast<const short8*>(W2p);
  const short8* C1f = reinterpret_cast<const short8*>(C1p);
  const int wrow = e*38;

  // constant-1 B-frag (k==64 slot) for bias rows of GEMM2/3
  short8 ones8 = {0,0,0,0,0,0,0,0};
  if (h == 0) ones8[0] = (short)0x3F80;

  // GEMM1: bias folded at k=131 (weights pre-scaled by SCL); both-mt ILP
  {
    short8 bf[9];
    #pragma unroll
    for (int kt = 0; kt < 4; ++kt)
      bf[kt] = *reinterpret_cast<const short8*>(hb + (size_t)rA*HD + kt*16 + h*8);
    #pragma unroll
    for (int kt = 0; kt < 4; ++kt)
      bf[4+kt] = *reinterpret_cast<const short8*>(hb + (size_t)cA*HD + kt*16 + h*8);
    short8 t8 = {0,0,0,0,0,0,0,0};
    if (h == 0){
      t8[0] = (short)f2b(radial);
      t8[1] = (short)f2b(__int_as_float(er.z));
      t8[2] = (short)f2b(__int_as_float(er.w));
      t8[3] = (short)0x3F80;   // 1.0 -> pairs with b1*SCL packed at k=131
    }
    bf[8] = t8;

    f32x16 a0, a1;
    #pragma unroll
    for (int r = 0; r < 16; ++r){ a0[r] = 0.0f; a1[r] = 0.0f; }
    __builtin_amdgcn_s_setprio(1);
    #pragma unroll
    for (int kt = 0; kt < 9; ++kt)
      a0 = __builtin_amdgcn_mfma_f32_32x32x16_bf16(W1f[(kt*2+0)*64 + lane], bf[kt], a0, 0,0,0);
    #pragma unroll
    for (int kt = 0; kt < 9; ++kt)
      a1 = __builtin_amdgcn_mfma_f32_32x32x16_bf16(W1f[(kt*2+1)*64 + lane], bf[kt], a1, 0,0,0);
    __builtin_amdgcn_s_setprio(0);
    #pragma unroll
    for (int q = 0; q < 4; ++q){
      uint u0 = pk2(silu_s(a0[4*q+0]), silu_s(a0[4*q+1]));
      uint u1 = pk2(silu_s(a0[4*q+2]), silu_s(a0[4*q+3]));
      *reinterpret_cast<uint2v*>(&XMT[wrow + q*4 + h*2]) = (uint2v){u0, u1};
    }
    #pragma unroll
    for (int q = 0; q < 4; ++q){
      uint u0 = pk2(silu_s(a1[4*q+0]), silu_s(a1[4*q+1]));
      uint u1 = pk2(silu_s(a1[4*q+2]), silu_s(a1[4*q+3]));
      *reinterpret_cast<uint2v*>(&XMT[wrow + 16 + q*4 + h*2]) = (uint2v){u0, u1};
    }
  }
  __builtin_amdgcn_sched_barrier(0);

  // GEMM2: m = silu(X1 @ W2 + b2), K=80 (bias row at k=64); both-mt ILP
  {
    short8 xf[4];
    #pragma unroll
    for (int kt = 0; kt < 4; ++kt)
      xf[kt] = *reinterpret_cast<const short8*>(&XMT[wrow + kt*8 + h*4]);
    f32x16 a0, a1;
    #pragma unroll
    for (int r = 0; r < 16; ++r){ a0[r] = 0.0f; a1[r] = 0.0f; }
    __builtin_amdgcn_s_setprio(1);
    #pragma unroll
    for (int kt = 0; kt < 4; ++kt)
      a0 = __builtin_amdgcn_mfma_f32_32x32x16_bf16(W2f[(kt*2+0)*64 + lane], xf[kt], a0, 0,0,0);
    a0 = __builtin_amdgcn_mfma_f32_32x32x16_bf16(W2f[(4*2+0)*64 + lane], ones8, a0, 0,0,0);
    #pragma unroll
    for (int kt = 0; kt < 4; ++kt)
      a1 = __builtin_amdgcn_mfma_f32_32x32x16_bf16(W2f[(kt*2+1)*64 + lane], xf[kt], a1, 0,0,0);
    a1 = __builtin_amdgcn_mfma_f32_32x32x16_bf16(W2f[(4*2+1)*64 + lane], ones8, a1, 0,0,0);
    __builtin_amdgcn_s_setprio(0);
    #pragma unroll
    for (int q = 0; q < 4; ++q){
      uint u0 = pk2(silu_s(a0[4*q+0]), silu_s(a0[4*q+1]));
      uint u1 = pk2(silu_s(a0[4*q+2]), silu_s(a0[4*q+3]));
      *reinterpret_cast<uint2v*>(&XMT[wrow + q*4 + h*2]) = (uint2v){u0, u1};
    }
    #pragma unroll
    for (int q = 0; q < 4; ++q){
      uint u0 = pk2(silu_s(a1[4*q+0]), silu_s(a1[4*q+1]));
      uint u1 = pk2(silu_s(a1[4*q+2]), silu_s(a1[4*q+3]));
      *reinterpret_cast<uint2v*>(&XMT[wrow + 16 + q*4 + h*2]) = (uint2v){u0, u1};
    }
  }
  __builtin_amdgcn_sched_barrier(0);

  // GEMM3: X3 = silu(m @ cW1 + cb1), K=80 ; w = (X3s @ cw2) * LN2 ; both-mt ILP
  float pw = 0.0f;
  {
    short8 xg[4];
    #pragma unroll
    for (int kt = 0; kt < 4; ++kt)
      xg[kt] = *reinterpret_cast<const short8*>(&XMT[wrow + kt*8 + h*4]);
    f32x16 a0, a1;
    #pragma unroll
    for (int r = 0; r < 16; ++r){ a0[r] = 0.0f; a1[r] = 0.0f; }
    __builtin_amdgcn_s_setprio(1);
    #pragma unroll
    for (int kt = 0; kt < 4; ++kt)
      a0 = __builtin_amdgcn_mfma_f32_32x32x16_bf16(C1f[(kt*2+0)*64 + lane], xg[kt], a0, 0,0,0);
    a0 = __builtin_amdgcn_mfma_f32_32x32x16_bf16(C1f[(4*2+0)*64 + lane], ones8, a0, 0,0,0);
    #pragma unroll
    for (int kt = 0; kt < 4; ++kt)
      a1 = __builtin_amdgcn_mfma_f32_32x32x16_bf16(C1f[(kt*2+1)*64 + lane], xg[kt], a1, 0,0,0);
    a1 = __builtin_amdgcn_mfma_f32_32x32x16_bf16(C1f[(4*2+1)*64 + lane], ones8, a1, 0,0,0);
    __builtin_amdgcn_s_setprio(0);
    #pragma unroll
    for (int q = 0; q < 4; ++q){
      f32x4 cwq = *reinterpret_cast<const f32x4*>(cw2 + q*8 + h*4);
      #pragma unroll
      for (int r = 0; r < 4; ++r) pw += silu_s(a0[4*q+r]) * cwq[r];
    }
    #pragma unroll
    for (int q = 0; q < 4; ++q){
      f32x4 cwq = *reinterpret_cast<const f32x4*>(cw2 + 32 + q*8 + h*4);
      #pragma unroll
      for (int r = 0; r < 4; ++r) pw += silu_s(a1[4*q+r]) * cwq[r];
    }
  }
  pw += __shfl_xor(pw, 32);
  pw *= LN2;   // undo SCL carried by X3
  if (h == 0){
    // trans -> XMT spare columns (uints 32..34 of this edge's row)
    *reinterpret_cast<uint2v*>(&XMT[wrow + 32]) =
        (uint2v){__float_as_uint(dx*pw), __float_as_uint(dy*pw)};
    XMT[wrow + 34] = __float_as_uint(dz*pw);
  }
  __builtin_amdgcn_sched_barrier(0);

  // per-wave segmented sum over 32 CSR-sorted edges.
  // m values carry SCL; k_node's nW1 agg rows are pre-divided by SCL.
  // Interior segments are wave-exclusive (CSR) -> plain store.
  const ushort* mvals = reinterpret_cast<const ushort*>(XMT);
  const float*  tvals = reinterpret_cast<const float*>(XMT);
  float sum = 0.f, ts = 0.f;
  int rcur = __builtin_amdgcn_readlane(rA, 0);
  int segstart = 0;
  #pragma unroll
  for (int i = 0; i < 32; ++i){
    sum += b2f(mvals[i*76 + lane]);
    if (lane < 3) ts += tvals[i*38 + 32 + lane];
    int rnext = (i < 31) ? __builtin_amdgcn_readlane(rA, i+1) : -1;
    if (rnext != rcur){
      if (segstart == 0 || i == 31){
        atomicAdd(&aggf[(size_t)rcur*AGS + lane], sum);
        if (lane < 3) atomicAdd(&aggf[(size_t)rcur*AGS + 64 + lane], ts);
      } else {
        aggf[(size_t)rcur*AGS + lane] = sum;
        if (lane < 3) aggf[(size_t)rcur*AGS + 64 + lane] = ts;
      }
      sum = 0.f; ts = 0.f; rcur = rnext; segstart = i + 1;
    }
  }
}

// ---------------- node MFMA kernel (+fused vel/coord update, +aggf re-zero) ----------------
__global__ __launch_bounds__(256) void k_node(
    const ushort* __restrict__ hb, float* __restrict__ aggf, const float* __restrict__ h_in,
    const ushort* __restrict__ nW1p, const ushort* __restrict__ nW2p, const ushort* __restrict__ vW1p,
    const float* __restrict__ nb1, const float* __restrict__ nb2,
    const float* __restrict__ vb1, const float* __restrict__ vW2, const float* __restrict__ vb2,
    const int* __restrict__ counts, float4* __restrict__ velw4, float4* __restrict__ coordw4,
    float* __restrict__ h_out, ushort* __restrict__ hb_out,
    float* __restrict__ xout, float* __restrict__ vout, int last)
{
  __shared__ __align__(16) ushort HID[64*88];
  __shared__ float VS[64];
  const int tid = threadIdx.x;
  const int wave = tid >> 6, lane = tid & 63;
  const int c = lane & 15, g = lane >> 4;
  const int wt = wave * 16;
  const int nbase = blockIdx.x * 64;
  int nA = nbase + wt + c;
  int nAc = (nA < NN) ? nA : (NN-1);

  short8 af[4];
  af[0] = *reinterpret_cast<const short8*>(hb + (size_t)nAc*HD + g*8);
  af[1] = *reinterpret_cast<const short8*>(hb + (size_t)nAc*HD + 32 + g*8);
  {
    const float* ag = aggf + (size_t)nAc*AGS;
    f32x4 q0 = *reinterpret_cast<const f32x4*>(ag + g*8);
    f32x4 q1 = *reinterpret_cast<const f32x4*>(ag + g*8 + 4);
    f32x4 q2 = *reinterpret_cast<const f32x4*>(ag + 32 + g*8);
    f32x4 q3 = *reinterpret_cast<const f32x4*>(ag + 32 + g*8 + 4);
    union FB { ushort u[8]; short8 s; };
    FB f2_, f3_;
    #pragma unroll
    for (int i = 0; i < 4; ++i){ f2_.u[i] = f2b(q0[i]); f2_.u[4+i] = f2b(q1[i]); }
    #pragma unroll
    for (int i = 0; i < 4; ++i){ f3_.u[i] = f2b(q2[i]); f3_.u[4+i] = f2b(q3[i]); }
    af[2] = f2_.s;
    af[3] = f3_.s;
  }
  const short8* N1f = reinterpret_cast<const short8*>(nW1p);
  const short8* N2f = reinterpret_cast<const short8*>(nW2p);
  const short8* V1f = reinterpret_cast<const short8*>(vW1p);

  f32x4 acc[4];
  #pragma unroll
  for (int ct = 0; ct < 4; ++ct){
    float bb = nb1[ct*16 + c];
    acc[ct] = (f32x4){bb,bb,bb,bb};
  }
  #pragma unroll
  for (int kt = 0; kt < 4; ++kt){
    #pragma unroll
    for (int ct = 0; ct < 4; ++ct){
      acc[ct] = __builtin_amdgcn_mfma_f32_16x16x32_bf16(af[kt], N1f[(kt*4+ct)*64 + lane], acc[ct], 0,0,0);
    }
  }
  #pragma unroll
  for (int ct = 0; ct < 4; ++ct){
    int col = ct*16 + c;
    #pragma unroll
    for (int r = 0; r < 4; ++r){
      HID[(wt + g*4 + r)*88 + col] = f2b(silu_f(acc[ct][r]));
    }
  }

  // v MLP (uses h only)
  f32x4 av[4];
  #pragma unroll
  for (int ct = 0; ct < 4; ++ct){
    float bb = vb1[ct*16 + c];
    av[ct] = (f32x4){bb,bb,bb,bb};
  }
  #pragma unroll
  for (int kt = 0; kt < 2; ++kt){
    #pragma unroll
    for (int ct = 0; ct < 4; ++ct){
      av[ct] = __builtin_amdgcn_mfma_f32_16x16x32_bf16(af[kt], V1f[(kt*4+ct)*64 + lane], av[ct], 0,0,0);
    }
  }
  float pw[4] = {0.f,0.f,0.f,0.f};
  #pragma unroll
  for (int ct = 0; ct < 4; ++ct){
    float vw = vW2[ct*16 + c];
    #pragma unroll
    for (int r = 0; r < 4; ++r) pw[r] += silu_f(av[ct][r]) * vw;
  }
  #pragma unroll
  for (int off = 1; off < 16; off <<= 1){
    #pragma unroll
    for (int r = 0; r < 4; ++r) pw[r] += __shfl_xor(pw[r], off, 16);
  }
  if (c == 0){
    float vbias = vb2[0];
    #pragma unroll
    for (int r = 0; r < 4; ++r) VS[wt + g*4 + r] = pw[r] + vbias;
  }

  // node MLP second layer (reads HID written by this wave only)
  short8 h0 = *reinterpret_cast<const short8*>(&HID[(wt + c)*88 + g*8]);
  short8 h1 = *reinterpret_cast<const short8*>(&HID[(wt + c)*88 + 32 + g*8]);
  f32x4 a2[4];
  #pragma unroll
  for (int ct = 0; ct < 4; ++ct){
    float bb = nb2[ct*16 + c];
    a2[ct] = (f32x4){bb,bb,bb,bb};
  }
  #pragma unroll
  for (int ct = 0; ct < 4; ++ct)
    a2[ct] = __builtin_amdgcn_mfma_f32_16x16x32_bf16(h0, N2f[(0*4+ct)*64 + lane], a2[ct], 0,0,0);
  #pragma unroll
  for (int ct = 0; ct < 4; ++ct)
    a2[ct] = __builtin_amdgcn_mfma_f32_16x16x32_bf16(h1, N2f[(1*4+ct)*64 + lane], a2[ct], 0,0,0);
  #pragma unroll
  for (int ct = 0; ct < 4; ++ct){
    int col = ct*16 + c;
    #pragma unroll
    for (int r = 0; r < 4; ++r){
      int n = nbase + wt + g*4 + r;
      if (n < NN){
        size_t off = (size_t)n*HD + col;
        float v = 2.0f*h_in[off] + a2[ct][r];
        h_out[off] = v;
        hb_out[off] = f2b(v);
      }
    }
  }

  // fused vel/coord update
  __syncthreads();
  if (tid < 64){
    int n = nbase + tid;
    if (n < NN){
      float vsn = VS[tid];
      float inv = 1.0f / fmaxf((float)counts[n], 1.0f);
      const float* ag = aggf + (size_t)n*AGS + 64;
      float ax = ag[0]*inv, ay = ag[1]*inv, az = ag[2]*inv;
      float4 vv = velw4[n];
      float4 cc = coordw4[n];
      float v0 = vsn*vv.x + ax*(1.0f/7.0f);
      float v1 = vsn*vv.y + ay*(1.0f/7.0f);
      float v2 = vsn*vv.z + az*(1.0f/7.0f);
      float s = vv.w / (sqrtf(v0*v0 + v1*v1 + v2*v2) + 1e-8f);
      v0 *= s; v1 *= s; v2 *= s;
      float c0 = cc.x + v0*(1.0f/7.0f);
      float c1 = cc.y + v1*(1.0f/7.0f);
      float c2 = cc.z + v2*(1.0f/7.0f);
      if (last){
        vout[n*3+0] = v0; vout[n*3+1] = v1; vout[n*3+2] = v2;
        xout[n*3+0] = c0; xout[n*3+1] = c1; xout[n*3+2] = c2;
      } else {
        velw4[n] = make_float4(v0, v1, v2, vv.w);
        coordw4[n] = make_float4(c0, c1, c2, 0.0f);
      }
    }
  }

  // re-zero this block's aggf rows for the next layer (vectorized)
  __syncthreads();
  int nvalid = NN - nbase; if (nvalid > 64) nvalid = 64;
  f32x4* zb4 = reinterpret_cast<f32x4*>(aggf + (size_t)nbase*AGS);
  f32x4 z4 = {0.f,0.f,0.f,0.f};
  for (int idx2 = tid; idx2 < nvalid*(AGS/4); idx2 += 256) zb4[idx2] = z4;
}

// ---------------- launcher ----------------
extern "C" void kernel_launch(void* const* d_in, const int* in_sizes, int n_in,
                              void* d_out, int out_size, void* d_ws, size_t ws_size,
                              hipStream_t stream)
{
  const float* his  = (const float*)d_in[0];
  const float* loc  = (const float*)d_in[1];
  const int*   edges= (const int*)d_in[2];
  const float* vel0 = (const float*)d_in[3];
  const float* eatt = (const float*)d_in[4];
  const float* embW = (const float*)d_in[5];
  const float* embB = (const float*)d_in[6];
  const float* eW1  = (const float*)d_in[7];
  const float* eB1  = (const float*)d_in[8];
  const float* eW2  = (const float*)d_in[9];
  const float* eB2  = (const float*)d_in[10];
  const float* cW1  = (const float*)d_in[11];
  const float* cB1  = (const float*)d_in[12];
  const float* cW2  = (const float*)d_in[13];
  const float* vW1  = (const float*)d_in[14];
  const float* vB1  = (const float*)d_in[15];
  const float* vW2  = (const float*)d_in[16];
  const float* vB2  = (const float*)d_in[17];
  const float* nW1  = (const float*)d_in[18];
  const float* nB1  = (const float*)d_in[19];
  const float* nW2  = (const float*)d_in[20];
  const float* nB2  = (const float*)d_in[21];
  const int* erow = edges;
  const int* ecol = edges + EE;

  char* ws = (char*)d_ws;
  size_t off = 0;
  auto alloc = [&](size_t bytes)->char*{
    char* p = ws + off;
    off = (off + bytes + 255) & ~(size_t)255;
    return p;
  };
  ushort* hb     = (ushort*)alloc((size_t)NN*HD*2);
  int*    counts = (int*)   alloc((size_t)NN*4);       // counts..aggf contiguous: one memset
  float*  aggf   = (float*) alloc((size_t)NN*AGS*4);
  int*    cursor = (int*)   alloc((size_t)NN*4);
  int*    bsum   = (int*)   alloc(256*4);
  int*    bbase  = (int*)   alloc(256*4);
  float4* coordw4= (float4*)alloc((size_t)NN*16);
  float4* velw4  = (float4*)alloc((size_t)NN*16);
  ushort* allp   = (ushort*)alloc(35840*2);
  int4*   erec   = (int4*)  alloc((size_t)EE*16);

  ushort* eW1p32 = allp;            // 9216
  ushort* eW2p32 = allp + 9216;     // 5120 (K=80, bias row)
  ushort* cW1p32 = allp + 14336;    // 5120
  ushort* nW1p   = allp + 19456;    // 8192
  ushort* nW2p   = allp + 27648;    // 4096
  ushort* vW1p   = allp + 31744;    // 4096

  float* xout = (float*)d_out;                    // [N,3]
  float* hout = (float*)d_out + (size_t)NN*3;     // [N,64] — doubles as fp32 h buffer
  float* vout = (float*)d_out + (size_t)NN*3 + (size_t)NN*HD; // [N,3]

  // single memset spanning counts (incl. 256B pad) + aggf
  size_t counts_pad = ((size_t)NN*4 + 255) & ~(size_t)255;
  hipMemsetAsync(counts, 0, counts_pad + (size_t)NN*AGS*4, stream);
  k_prep<<<12500,256,0,stream>>>(erow, counts, loc, vel0, coordw4, velw4,
      his, embW, embB, hout, hb,
      eW1, eB1, eW2, eB2, cW1, cB1, nW1, nW2, vW1, allp);
  k_bsum<<<196,256,0,stream>>>(counts, bsum);
  k_bscan<<<1,256,0,stream>>>(bsum, bbase);
  k_scatter<<<196,256,0,stream>>>(counts, bbase, cursor);
  k_fill<<<3125,256,0,stream>>>(erow, ecol, eatt, cursor, erec);

  for (int L = 0; L < 4; ++L){
    k_edge<<<25000,64,0,stream>>>(hb, coordw4, erec,
        eW1p32, eW2p32, cW1p32, cW2, aggf);
    k_node<<<782,256,0,stream>>>(hb, aggf, hout, nW1p, nW2p, vW1p,
        nB1, nB2, vB1, vW2, vB2, counts, velw4, coordw4,
        hout, hb, xout, vout, (L==3) ? 1 : 0);
  }
}